// Round 13
// baseline (326.026 us; speedup 1.0000x reference)
//
#include <hip/hip_runtime.h>
#include <hip/hip_bf16.h>

typedef __bf16 bf16x8 __attribute__((ext_vector_type(8)));
typedef __bf16 bf16x4 __attribute__((ext_vector_type(4)));
typedef float  f32x4  __attribute__((ext_vector_type(4)));
typedef float  f32x16 __attribute__((ext_vector_type(16)));

// ---------------------------------------------------------------------------
// Kernel 1: prep (R9 form — validated)
// ---------------------------------------------------------------------------
__global__ __launch_bounds__(256) void prep_kernel(
    const float* __restrict__ img, const float* __restrict__ ques,
    const float* __restrict__ g_w1, const float* __restrict__ g_b1,
    const float* __restrict__ g_w2, const float* __restrict__ g_w3,
    const float* __restrict__ g_w4,
    float* __restrict__ U, float* __restrict__ V, float* __restrict__ Qb,
    __bf16* __restrict__ W2t, __bf16* __restrict__ W3t, __bf16* __restrict__ W4t) {
  __shared__ float smem[64 * 65];
  const int blk = blockIdx.x;
  const int t = threadIdx.x;

  if (blk < 512) {
    const int n = blk >> 3, obase = (blk & 7) * 8;
    for (int idx = t; idx < 66 * 8; idx += 256) {
      const int c = idx >> 3, o = obase + (idx & 7);
      float v;
      if (c < 64)      v = img[n * 4096 + c * 64 + o];
      else if (c == 64) v = (float)(o >> 3);
      else              v = (float)(o & 7);
      smem[idx] = v;
    }
    __syncthreads();
    float u[8], vv[8];
#pragma unroll
    for (int o = 0; o < 8; ++o) { u[o] = 0.f; vv[o] = 0.f; }
#pragma unroll 2
    for (int d = 0; d < 66; ++d) {
      const float wu = g_w1[d * 256 + t];
      const float wv = g_w1[(66 + d) * 256 + t];
#pragma unroll
      for (int o = 0; o < 8; ++o) {
        const float cc = smem[d * 8 + o];
        u[o]  += cc * wu;
        vv[o] += cc * wv;
      }
    }
#pragma unroll
    for (int o = 0; o < 8; ++o) {
      U[(size_t)(n * 64 + obase + o) * 256 + t] = u[o];
      V[(size_t)(n * 64 + obase + o) * 256 + t] = vv[o];
    }
  } else if (blk < 576) {
    const int n = blk - 512;
    smem[t] = ques[n * 256 + t];
    __syncthreads();
    float s = g_b1[t];
    for (int e = 0; e < 256; ++e) s += smem[e] * g_w1[(132 + e) * 256 + t];
    Qb[n * 256 + t] = s;
  } else {
    const int b2 = blk - 576;
    const int wsel = b2 >> 4;
    const int tile = b2 & 15;
    const int r0 = (tile >> 2) * 64, c0 = (tile & 3) * 64;
    const float* W = (wsel == 0) ? g_w2 : (wsel == 1) ? g_w3 : g_w4;
    __bf16* Wt    = (wsel == 0) ? W2t  : (wsel == 1) ? W3t  : W4t;
    const int col = t & 63, rb = (t >> 6) * 16;
#pragma unroll 4
    for (int j = 0; j < 16; ++j)
      smem[(rb + j) * 65 + col] = W[(size_t)(r0 + rb + j) * 256 + c0 + col];
    __syncthreads();
#pragma unroll 4
    for (int j = 0; j < 16; ++j)
      Wt[(size_t)(c0 + rb + j) * 256 + r0 + col] = (__bf16)smem[col * 65 + rb + j];
  }
}

// ---------------------------------------------------------------------------
// Kernel 2: fused g-MLP layers 2..4.
//  ROUND-12: 32x32x16 MFMA + 2x4 wave split (register-neutral LDS halving).
//   R11 proved LDS-read is ~70% of critical path (conflict drop tracked dur
//   1:0.7). Remaining volume structural: 8 waves x full 64KB H per layer.
//   FIX: wave (rw=nq>>2, cw=nq&3) owns 64 rows x 64 cols as 2x2 tiles of
//   32x32, K in 16 steps of 16:
//    - A-read traffic HALVES (32KB/wave/layer); MFMA pipe -17% (8.07cyc/32k
//      FLOP vs 4.85/16k); registers unchanged (acc 2x2xf32x16=64, bb 16).
//    - rw = i-object (rows 0-63 = i0, 64-127 = i1): LAST j-sum wave-local,
//      no cross-wave combine (fixes R1's flaw). W-dup 2x = negligible L2.
//   Fragment layout (chunk = 32 rows x 16 K = 1KB, 64 lanes x 16B contig):
//    - B-op (H): lane l -> j = l&31, k = (l>>5)*8+e  [analog of verified
//      16x16x32 mapping]; read addr = chunk*CH + lane*8, conflict-free.
//    - C/D (m74/m101-verified): col j = lane&31, out-col = (reg&3)+8*(reg>>2)
//      +4*(lane>>5). Epilogue reg-group rg -> bf16x4 at chunk (m*16 + cw*4 +
//      nt*2 + (rg>>1)), lane' = (rg&1)*32+l31, e' = 4*(lane>>5).
//   Rest: M=128, 512 thr / 8 waves, depth-2 bb, bias-in-acc-init, in-place H
//   (BAR1+BAR2), grid 2048, (512,4). LDS 66560 B -> 2 blocks/CU.
// ---------------------------------------------------------------------------
#define CH 520     // bf16 elems per chunk (512 data + 8 pad)

template <bool LAST>
__device__ __forceinline__ void g_layer(__bf16* Hs,
                                        bf16x8 bb[2][2],
                                        const __bf16* __restrict__ Wcur,
                                        const __bf16* __restrict__ Wnext,
                                        int woff, int rbase, int wchunk,
                                        int wlane, int cbb,
                                        const float* __restrict__ bias_g,
                                        int rw, int l31,
                                        float* __restrict__ pr0,
                                        float* __restrict__ pr1) {
  f32x16 acc[2][2];
  // bias folded into acc init: out-col = cbb + nt*32 + rg*8 + (reg&3)
#pragma unroll
  for (int nt = 0; nt < 2; ++nt)
#pragma unroll
    for (int rg = 0; rg < 4; ++rg) {
      const f32x4 bv = *(const f32x4*)&bias_g[cbb + nt * 32 + rg * 8];
#pragma unroll
      for (int j = 0; j < 4; ++j) {
        acc[0][nt][rg * 4 + j] = bv[j];
        acc[1][nt][rg * 4 + j] = bv[j];
      }
    }

#pragma unroll
  for (int ks = 0; ks < 16; ++ks) {
    const bf16x8 b0 = bb[ks & 1][0];
    const bf16x8 b1 = bb[ks & 1][1];
    // refill other slot: 1 K-step ahead; at ks=15 load next layer's ks=0
    // (16 even -> slot parity consistent across layers)
    if (ks < 15) {
      bb[(ks + 1) & 1][0] = *(const bf16x8*)&Wcur[woff + (ks + 1) * 16];
      bb[(ks + 1) & 1][1] = *(const bf16x8*)&Wcur[woff + 8192 + (ks + 1) * 16];
    } else if (!LAST) {
      bb[0][0] = *(const bf16x8*)&Wnext[woff];
      bb[0][1] = *(const bf16x8*)&Wnext[woff + 8192];
    }
    // contiguous 1KB wave reads: chunks (rw*2+m)*16 + ks
    const bf16x8 a0 = *(const bf16x8*)&Hs[rbase + ks * CH];
    const bf16x8 a1 = *(const bf16x8*)&Hs[rbase + (16 + ks) * CH];
    // swapped operands: D[out-col][j] = sum_k W[out-col][k] * H[j][k]
    acc[0][0] = __builtin_amdgcn_mfma_f32_32x32x16_bf16(b0, a0, acc[0][0], 0, 0, 0);
    acc[0][1] = __builtin_amdgcn_mfma_f32_32x32x16_bf16(b1, a0, acc[0][1], 0, 0, 0);
    acc[1][0] = __builtin_amdgcn_mfma_f32_32x32x16_bf16(b0, a1, acc[1][0], 0, 0, 0);
    acc[1][1] = __builtin_amdgcn_mfma_f32_32x32x16_bf16(b1, a1, acc[1][1], 0, 0, 0);
  }

  if (!LAST) {
    __syncthreads();   // BAR1: all waves finished reading Hs -> in-place safe
#pragma unroll
    for (int m = 0; m < 2; ++m)
#pragma unroll
      for (int nt = 0; nt < 2; ++nt)
#pragma unroll
        for (int rg = 0; rg < 4; ++rg) {
          bf16x4 h;
#pragma unroll
          for (int j = 0; j < 4; ++j)
            h[j] = (__bf16)fmaxf(acc[m][nt][rg * 4 + j], 0.f);
          *(bf16x4*)&Hs[wchunk + (m * 16 + nt * 2 + (rg >> 1)) * CH
                        + wlane + (rg & 1) * 256] = h;
        }
    __syncthreads();   // BAR2: stores visible before next layer's reads
  } else {
    // j-sum: wave's 2 m-tiles ARE its complete i-object (rw = i)
    float* pr = rw ? pr1 : pr0;
#pragma unroll
    for (int nt = 0; nt < 2; ++nt) {
      float s[16];
#pragma unroll
      for (int e = 0; e < 16; ++e)
        s[e] = fmaxf(acc[0][nt][e], 0.f) + fmaxf(acc[1][nt][e], 0.f);
#pragma unroll
      for (int d = 1; d <= 16; d <<= 1) {
#pragma unroll
        for (int e = 0; e < 16; ++e) s[e] += __shfl_xor(s[e], d, 64);
      }
      if (l31 == 0) {
#pragma unroll
        for (int rg = 0; rg < 4; ++rg) {
          f32x4 v;
          v[0] = s[rg * 4 + 0]; v[1] = s[rg * 4 + 1];
          v[2] = s[rg * 4 + 2]; v[3] = s[rg * 4 + 3];
          *(f32x4*)&pr[cbb + nt * 32 + rg * 8] = v;
        }
      }
    }
  }
}

__global__ __launch_bounds__(512, 4) void rn_main(
    const float* __restrict__ U, const float* __restrict__ V,
    const float* __restrict__ Qb,
    const __bf16* __restrict__ W2t, const __bf16* __restrict__ W3t,
    const __bf16* __restrict__ W4t,
    const float* __restrict__ b2, const float* __restrict__ b3,
    const float* __restrict__ b4,
    float* __restrict__ part) {
  __shared__ __align__(16) __bf16 Hs[64 * CH];   // 65 KB fragment-order H
  const int blk = blockIdx.x;
  const int nimg = blk >> 5, ipair = blk & 31;
  const int iobj0 = ipair * 2;
  const int t = threadIdx.x;
  const int nq = t >> 6, lane = t & 63;
  const int rw = nq >> 2, cw = nq & 3;
  const int l31 = lane & 31, lhi = lane >> 5;

  // W A-operand: lane l -> out-col row i = cw*64 + nt*32 + l31, k off lhi*8
  const int woff = (cw * 64 + l31) * 256 + lhi * 8;
  const int rbase  = rw * 32 * CH + lane * 8;          // K-loop read base
  const int wchunk = (rw * 32 + cw * 4) * CH;          // epilogue chunk base
  const int wlane  = l31 * 8 + lhi * 4;                // epilogue lane slot
  const int cbb    = cw * 64 + lhi * 4;                // col base (bias/part)

  // b double-buffer: preload layer-2 ks=0 (overlaps phase-0 loads/math)
  bf16x8 bb[2][2];
  bb[0][0] = *(const bf16x8*)&W2t[woff];
  bb[0][1] = *(const bf16x8*)&W2t[woff + 8192];

  // phase 0: rows 0-63 -> i0, rows 64-127 -> i1
  // h1[row][:] = relu(U[n, i(row), :] + V[n, j(row), :] + Qb[n, :])
  {
    const int c4 = t & 63;          // 4-float col group (k = c4*4 .. +3)
    const int rb = t >> 6;          // 16-row group (rows rb*16 .. +15)
    const int isel = rb >> 2;       // 0 or 1 (static per thread)
    // fragment target: chunk (rb>>1)*16 + (c4>>2); lane' = ((c4>>1)&1)*32 +
    // (rb&1)*16 + jj; e base (c4&1)*4
    const int pb = ((rb >> 1) * 16 + (c4 >> 2)) * CH
                 + (((c4 >> 1) & 1) * 32 + (rb & 1) * 16) * 8 + (c4 & 1) * 4;
    const f32x4 u4 = *(const f32x4*)&U[(size_t)(nimg * 64 + iobj0 + isel) * 256 + c4 * 4];
    const f32x4 q4 = *(const f32x4*)&Qb[(size_t)nimg * 256 + c4 * 4];
    const f32x4 uq = u4 + q4;
#pragma unroll
    for (int jj = 0; jj < 16; ++jj) {
      const int j = (rb & 3) * 16 + jj;
      const f32x4 v4 = *(const f32x4*)&V[(size_t)(nimg * 64 + j) * 256 + c4 * 4];
      bf16x4 h;
#pragma unroll
      for (int r = 0; r < 4; ++r) h[r] = (__bf16)fmaxf(uq[r] + v4[r], 0.f);
      *(bf16x4*)&Hs[pb + jj * 8] = h;
    }
  }
  __syncthreads();

  // part rows: global i-row index = nimg*64 + iobj0 (+1) = blk*2 (+1)
  float* pr0 = part + (size_t)blk * 512;
  float* pr1 = pr0 + 256;

  g_layer<false>(Hs, bb, W2t, W3t, woff, rbase, wchunk, wlane, cbb, b2, rw, l31, pr0, pr1);
  g_layer<false>(Hs, bb, W3t, W4t, woff, rbase, wchunk, wlane, cbb, b3, rw, l31, pr0, pr1);
  g_layer<true >(Hs, bb, W4t, W4t, woff, rbase, wchunk, wlane, cbb, b4, rw, l31, pr0, pr1);
}

// ---------------------------------------------------------------------------
// Kernel 3: reduce partials -> context, f-MLP (fp32), log_softmax.
// (R9 split-K form — validated)
// ---------------------------------------------------------------------------
__global__ __launch_bounds__(1024) void rn_final(
    const float* __restrict__ part,
    const float* __restrict__ f_w1, const float* __restrict__ f_b1,
    const float* __restrict__ f_w2, const float* __restrict__ f_b2,
    const float* __restrict__ f_w3, const float* __restrict__ f_b3,
    float* __restrict__ out) {
  __shared__ float red[4][256];
  __shared__ float ctx[256], y1[256], y2[256], sc[2];
  const int n = blockIdx.x;
  const int tid = threadIdx.x;
  const int o = tid & 255, g = tid >> 8;   // g in 0..3

  {
    float s = 0.f;
#pragma unroll 4
    for (int i = 0; i < 16; ++i)
      s += part[((size_t)n * 64 + g * 16 + i) * 256 + o];
    red[g][o] = s;
  }
  __syncthreads();
  if (g == 0)
    ctx[o] = (red[0][o] + red[1][o] + red[2][o] + red[3][o]) * (1.0f / 4096.0f);
  __syncthreads();

  {
    float a = 0.f;
#pragma unroll 4
    for (int k = 0; k < 64; ++k)
      a += ctx[g * 64 + k] * f_w1[(g * 64 + k) * 256 + o];
    red[g][o] = a;
  }
  __syncthreads();
  if (g == 0)
    y1[o] = fmaxf(red[0][o] + red[1][o] + red[2][o] + red[3][o] + f_b1[o], 0.f);
  __syncthreads();

  {
    float a = 0.f;
#pragma unroll 4
    for (int k = 0; k < 64; ++k)
      a += y1[g * 64 + k] * f_w2[(g * 64 + k) * 256 + o];
    red[g][o] = a;
  }
  __syncthreads();
  if (g == 0)
    y2[o] = fmaxf(red[0][o] + red[1][o] + red[2][o] + red[3][o] + f_b2[o], 0.f);
  __syncthreads();

  if (tid < 2) {
    float c = f_b3[tid];
    for (int k = 0; k < 256; ++k) c += y2[k] * f_w3[k * 2 + tid];
    sc[tid] = c;
  }
  __syncthreads();
  if (tid == 0) {
    const float s0 = sc[0], s1 = sc[1];
    const float mx = fmaxf(s0, s1);
    const float lse = mx + logf(expf(s0 - mx) + expf(s1 - mx));
    out[n * 2 + 0] = s0 - lse;
    out[n * 2 + 1] = s1 - lse;
  }
}

// ---------------------------------------------------------------------------
extern "C" void kernel_launch(void* const* d_in, const int* in_sizes, int n_in,
                              void* d_out, int out_size, void* d_ws, size_t ws_size,
                              hipStream_t stream) {
  const float* img  = (const float*)d_in[0];
  const float* ques = (const float*)d_in[1];
  const float* g_w1 = (const float*)d_in[2];
  const float* g_b1 = (const float*)d_in[3];
  const float* g_w2 = (const float*)d_in[4];
  const float* g_b2 = (const float*)d_in[5];
  const float* g_w3 = (const float*)d_in[6];
  const float* g_b3 = (const float*)d_in[7];
  const float* g_w4 = (const float*)d_in[8];
  const float* g_b4 = (const float*)d_in[9];
  const float* f_w1 = (const float*)d_in[10];
  const float* f_b1 = (const float*)d_in[11];
  const float* f_w2 = (const float*)d_in[12];
  const float* f_b2 = (const float*)d_in[13];
  const float* f_w3 = (const float*)d_in[14];
  const float* f_b3 = (const float*)d_in[15];
  float* out = (float*)d_out;

  char* ws = (char*)d_ws;
  float*  U    = (float*)(ws);                                 // 4 MB
  float*  V    = (float*)(ws + (size_t)4  * 1048576);          // 4 MB
  float*  part = (float*)(ws + (size_t)8  * 1048576);          // 4 MB
  float*  Qb   = (float*)(ws + (size_t)12 * 1048576);          // 64 KB
  __bf16* W2t  = (__bf16*)(ws + (size_t)12 * 1048576 + 65536); // 128 KB each
  __bf16* W3t  = W2t + 65536;
  __bf16* W4t  = W3t + 65536;

  prep_kernel<<<624, 256, 0, stream>>>(img, ques, g_w1, g_b1, g_w2, g_w3, g_w4,
                                       U, V, Qb, W2t, W3t, W4t);
  rn_main<<<2048, 512, 0, stream>>>(U, V, Qb, W2t, W3t, W4t, g_b2, g_b3, g_b4, part);
  rn_final<<<64, 1024, 0, stream>>>(part, f_w1, f_b1, f_w2, f_b2, f_w3, f_b3, out);
}

// Round 15
// 219.899 us; speedup vs baseline: 1.4826x; 1.4826x over previous
//
#include <hip/hip_runtime.h>
#include <hip/hip_bf16.h>

typedef __bf16 bf16x8 __attribute__((ext_vector_type(8)));
typedef __bf16 bf16x4 __attribute__((ext_vector_type(4)));
typedef float  f32x4  __attribute__((ext_vector_type(4)));

// ---------------------------------------------------------------------------
// Kernel 1: prep. ROUND-13: U/V branch 512 -> 1024 blocks (4 objects each):
// halves the per-block dependent chain again (prep is the largest non-main
// kernel; R9's 256->512 split was the only non-main change that helped).
// Qb / W-transpose branches logic unchanged (block indices shifted).
// ---------------------------------------------------------------------------
__global__ __launch_bounds__(256) void prep_kernel(
    const float* __restrict__ img, const float* __restrict__ ques,
    const float* __restrict__ g_w1, const float* __restrict__ g_b1,
    const float* __restrict__ g_w2, const float* __restrict__ g_w3,
    const float* __restrict__ g_w4,
    float* __restrict__ U, float* __restrict__ V, float* __restrict__ Qb,
    __bf16* __restrict__ W2t, __bf16* __restrict__ W3t, __bf16* __restrict__ W4t) {
  __shared__ float smem[64 * 65];
  const int blk = blockIdx.x;
  const int t = threadIdx.x;

  if (blk < 1024) {
    const int n = blk >> 4, obase = (blk & 15) * 4;
    for (int idx = t; idx < 66 * 4; idx += 256) {
      const int c = idx >> 2, o = obase + (idx & 3);
      float v;
      if (c < 64)      v = img[n * 4096 + c * 64 + o];
      else if (c == 64) v = (float)(o >> 3);
      else              v = (float)(o & 7);
      smem[idx] = v;
    }
    __syncthreads();
    float u[4], vv[4];
#pragma unroll
    for (int o = 0; o < 4; ++o) { u[o] = 0.f; vv[o] = 0.f; }
#pragma unroll 2
    for (int d = 0; d < 66; ++d) {
      const float wu = g_w1[d * 256 + t];
      const float wv = g_w1[(66 + d) * 256 + t];
#pragma unroll
      for (int o = 0; o < 4; ++o) {
        const float cc = smem[d * 4 + o];
        u[o]  += cc * wu;
        vv[o] += cc * wv;
      }
    }
#pragma unroll
    for (int o = 0; o < 4; ++o) {
      U[(size_t)(n * 64 + obase + o) * 256 + t] = u[o];
      V[(size_t)(n * 64 + obase + o) * 256 + t] = vv[o];
    }
  } else if (blk < 1088) {
    const int n = blk - 1024;
    smem[t] = ques[n * 256 + t];
    __syncthreads();
    float s = g_b1[t];
    for (int e = 0; e < 256; ++e) s += smem[e] * g_w1[(132 + e) * 256 + t];
    Qb[n * 256 + t] = s;
  } else {
    const int b2 = blk - 1088;
    const int wsel = b2 >> 4;
    const int tile = b2 & 15;
    const int r0 = (tile >> 2) * 64, c0 = (tile & 3) * 64;
    const float* W = (wsel == 0) ? g_w2 : (wsel == 1) ? g_w3 : g_w4;
    __bf16* Wt    = (wsel == 0) ? W2t  : (wsel == 1) ? W3t  : W4t;
    const int col = t & 63, rb = (t >> 6) * 16;
#pragma unroll 4
    for (int j = 0; j < 16; ++j)
      smem[(rb + j) * 65 + col] = W[(size_t)(r0 + rb + j) * 256 + c0 + col];
    __syncthreads();
#pragma unroll 4
    for (int j = 0; j < 16; ++j)
      Wt[(size_t)(c0 + rb + j) * 256 + r0 + col] = (__bf16)smem[col * 65 + rb + j];
  }
}

// ---------------------------------------------------------------------------
// Kernel 2: fused g-MLP layers 2..4.  ROUND-13 = R11 VERBATIM (the frontier).
//  R12 (32x32 + 2x4 split) refuted the LDS-volume-reduction direction a third
//  time: 16 refill points x (200cyc L2 - 32cyc MFMA issue) exposure, 4 serial
//  acc chains, f32x16 epilogue spill -> 239us. R11's balance — 8 refill
//  points x 78cyc issue, 16 indep chains, spill-free — is the local optimum.
//  FRAGMENT-NATIVE H LAYOUT (R11): chunk (m-tile 0..7, k-step 0..7) =
//  64 lanes x 16B contiguous (conflict-free wave read), stride 520 elems.
//    read  : Hs[(m*8+ks)*520 + lane*8]   (zero addr math in loop)
//    write : chunk nq, q' = 2nt+(q>>1), e = 4(q&1)+r
//    phase0: chunk c4>>3, q' = (c4>>1)&3, e = 4(c4&1)+r
//  M=128 (2 i-objects), 512 thr / 8 waves, depth-2 bb, bias-in-acc-init,
//  in-place H (BAR1+BAR2), grid 2048, (512,4). LDS 66560 B -> 2 blocks/CU.
//  Measured (R11): 128.5us main, conflicts 5.24e6, WRITE 4MB (spill-free),
//  MfmaUtil 34.8.
// ---------------------------------------------------------------------------
#define CH 520     // bf16 elems per chunk (512 data + 8 pad)

template <bool LAST>
__device__ __forceinline__ void g_layer(__bf16* Hs,
                                        bf16x8 bb[2][2],
                                        const __bf16* __restrict__ Wcur,
                                        const __bf16* __restrict__ Wnext,
                                        int woff, int lane8, int wb,
                                        const float* __restrict__ bias_g,
                                        int nq, int q, int r16,
                                        float* __restrict__ pr0,
                                        float* __restrict__ pr1) {
  f32x4 acc[8][2];
  {
    const f32x4 bv0 = *(const f32x4*)&bias_g[nq * 32 + 0 * 16 + q * 4];
    const f32x4 bv1 = *(const f32x4*)&bias_g[nq * 32 + 1 * 16 + q * 4];
#pragma unroll
    for (int m = 0; m < 8; ++m) {
      acc[m][0] = bv0;
      acc[m][1] = bv1;
    }
  }

#pragma unroll
  for (int ks = 0; ks < 8; ++ks) {
    const bf16x8 b0 = bb[ks & 1][0];
    const bf16x8 b1 = bb[ks & 1][1];
    // refill other slot: 1 K-step ahead; at ks=7 load next layer's ks=0
    if (ks < 7) {
      bb[(ks + 1) & 1][0] = *(const bf16x8*)&Wcur[woff + (ks + 1) * 32];
      bb[(ks + 1) & 1][1] = *(const bf16x8*)&Wcur[woff + 4096 + (ks + 1) * 32];
    } else if (!LAST) {
      bb[0][0] = *(const bf16x8*)&Wnext[woff];
      bb[0][1] = *(const bf16x8*)&Wnext[woff + 4096];
    }
#pragma unroll
    for (int m = 0; m < 8; ++m) {
      // contiguous 1KB wave read: chunk (m*8+ks), lane offset lane*8 elems
      const bf16x8 a = *(const bf16x8*)&Hs[(m * 8 + ks) * CH + lane8];
      // swapped operands (verified): acc[m][nt] -> row m*16+r16,
      // cols nq*32 + nt*16 + q*4 + reg
      acc[m][0] = __builtin_amdgcn_mfma_f32_16x16x32_bf16(b0, a, acc[m][0], 0, 0, 0);
      acc[m][1] = __builtin_amdgcn_mfma_f32_16x16x32_bf16(b1, a, acc[m][1], 0, 0, 0);
    }
  }

  if (!LAST) {
    __syncthreads();   // BAR1: all waves finished reading Hs -> in-place safe
#pragma unroll
    for (int m = 0; m < 8; ++m)
#pragma unroll
      for (int nt = 0; nt < 2; ++nt) {
        bf16x4 h;
#pragma unroll
        for (int r = 0; r < 4; ++r) h[r] = (__bf16)fmaxf(acc[m][nt][r], 0.f);
        // chunk nq, q' = 2nt+(q>>1), slot r16, e = 4(q&1)+r
        *(bf16x4*)&Hs[wb + m * (8 * CH) + nt * 256] = h;
      }
    __syncthreads();   // BAR2: stores visible before next layer's reads
  } else {
    // j-sum for both i halves: rows 0-63 (m 0..3) -> i0, 64-127 (m 4..7) -> i1
#pragma unroll
    for (int h = 0; h < 2; ++h) {
#pragma unroll
      for (int nt = 0; nt < 2; ++nt) {
        const int cb = nq * 32 + nt * 16 + q * 4;
        f32x4 s;
#pragma unroll
        for (int r = 0; r < 4; ++r)
          s[r] = fmaxf(acc[h * 4 + 0][nt][r], 0.f)
               + fmaxf(acc[h * 4 + 1][nt][r], 0.f)
               + fmaxf(acc[h * 4 + 2][nt][r], 0.f)
               + fmaxf(acc[h * 4 + 3][nt][r], 0.f);
#pragma unroll
        for (int d = 1; d < 16; d <<= 1) {
#pragma unroll
          for (int r = 0; r < 4; ++r) s[r] += __shfl_xor(s[r], d, 64);
        }
        if (r16 == 0) *(f32x4*)&(h ? pr1 : pr0)[cb] = s;
      }
    }
  }
}

__global__ __launch_bounds__(512, 4) void rn_main(
    const float* __restrict__ U, const float* __restrict__ V,
    const float* __restrict__ Qb,
    const __bf16* __restrict__ W2t, const __bf16* __restrict__ W3t,
    const __bf16* __restrict__ W4t,
    const float* __restrict__ b2, const float* __restrict__ b3,
    const float* __restrict__ b4,
    float* __restrict__ part) {
  __shared__ __align__(16) __bf16 Hs[64 * CH];   // 65 KB fragment-order H
  const int blk = blockIdx.x;
  const int nimg = blk >> 5, ipair = blk & 31;
  const int iobj0 = ipair * 2;
  const int t = threadIdx.x;
  const int nq = t >> 6, lane = t & 63;
  const int q = lane >> 4, r16 = lane & 15;

  // 32-bit weight offset (row = output col = nq*32 [+16] + r16, K off q*8)
  const int woff = (nq * 32 + r16) * 256 + q * 8;
  // LDS offsets: read = chunk base + lane8; write base wb (chunk nq)
  const int lane8 = lane * 8;
  const int wb = nq * CH + (q >> 1) * 128 + r16 * 8 + (q & 1) * 4;

  // b double-buffer: preload layer-2 ks=0 (overlaps phase-0 loads/math)
  bf16x8 bb[2][2];
  bb[0][0] = *(const bf16x8*)&W2t[woff];
  bb[0][1] = *(const bf16x8*)&W2t[woff + 4096];

  // phase 0: rows 0-63 -> i0, rows 64-127 -> i1
  // h1[row][:] = relu(U[n, i(row), :] + V[n, j(row), :] + Qb[n, :])
  {
    const int c4 = t & 63;          // 4-float col group (k = c4*4 .. +3)
    const int rb = t >> 6;          // m-tile 0..7 (rows rb*16 .. +15)
    const int isel = rb >> 2;       // 0 or 1 (static per thread)
    // fragment target: chunk rb*8 + (c4>>3), q' = (c4>>1)&3, e base 4*(c4&1)
    const int pb = (rb * 8 + (c4 >> 3)) * CH + ((c4 >> 1) & 3) * 128 + (c4 & 1) * 4;
    const f32x4 u4 = *(const f32x4*)&U[(size_t)(nimg * 64 + iobj0 + isel) * 256 + c4 * 4];
    const f32x4 q4 = *(const f32x4*)&Qb[(size_t)nimg * 256 + c4 * 4];
    const f32x4 uq = u4 + q4;
#pragma unroll
    for (int jj = 0; jj < 16; ++jj) {
      const int j = (rb & 3) * 16 + jj;
      const f32x4 v4 = *(const f32x4*)&V[(size_t)(nimg * 64 + j) * 256 + c4 * 4];
      bf16x4 h;
#pragma unroll
      for (int r = 0; r < 4; ++r) h[r] = (__bf16)fmaxf(uq[r] + v4[r], 0.f);
      *(bf16x4*)&Hs[pb + jj * 8] = h;   // slot jj within chunk
    }
  }
  __syncthreads();

  // part rows: global i-row index = nimg*64 + iobj0 (+1) = blk*2 (+1)
  float* pr0 = part + (size_t)blk * 512;
  float* pr1 = pr0 + 256;

  g_layer<false>(Hs, bb, W2t, W3t, woff, lane8, wb, b2, nq, q, r16, pr0, pr1);
  g_layer<false>(Hs, bb, W3t, W4t, woff, lane8, wb, b3, nq, q, r16, pr0, pr1);
  g_layer<true >(Hs, bb, W4t, W4t, woff, lane8, wb, b4, nq, q, r16, pr0, pr1);
}

// ---------------------------------------------------------------------------
// Kernel 3: reduce partials -> context, f-MLP (fp32), log_softmax.
// (R9 split-K form — validated)
// ---------------------------------------------------------------------------
__global__ __launch_bounds__(1024) void rn_final(
    const float* __restrict__ part,
    const float* __restrict__ f_w1, const float* __restrict__ f_b1,
    const float* __restrict__ f_w2, const float* __restrict__ f_b2,
    const float* __restrict__ f_w3, const float* __restrict__ f_b3,
    float* __restrict__ out) {
  __shared__ float red[4][256];
  __shared__ float ctx[256], y1[256], y2[256], sc[2];
  const int n = blockIdx.x;
  const int tid = threadIdx.x;
  const int o = tid & 255, g = tid >> 8;   // g in 0..3

  {
    float s = 0.f;
#pragma unroll 4
    for (int i = 0; i < 16; ++i)
      s += part[((size_t)n * 64 + g * 16 + i) * 256 + o];
    red[g][o] = s;
  }
  __syncthreads();
  if (g == 0)
    ctx[o] = (red[0][o] + red[1][o] + red[2][o] + red[3][o]) * (1.0f / 4096.0f);
  __syncthreads();

  {
    float a = 0.f;
#pragma unroll 4
    for (int k = 0; k < 64; ++k)
      a += ctx[g * 64 + k] * f_w1[(g * 64 + k) * 256 + o];
    red[g][o] = a;
  }
  __syncthreads();
  if (g == 0)
    y1[o] = fmaxf(red[0][o] + red[1][o] + red[2][o] + red[3][o] + f_b1[o], 0.f);
  __syncthreads();

  {
    float a = 0.f;
#pragma unroll 4
    for (int k = 0; k < 64; ++k)
      a += y1[g * 64 + k] * f_w2[(g * 64 + k) * 256 + o];
    red[g][o] = a;
  }
  __syncthreads();
  if (g == 0)
    y2[o] = fmaxf(red[0][o] + red[1][o] + red[2][o] + red[3][o] + f_b2[o], 0.f);
  __syncthreads();

  if (tid < 2) {
    float c = f_b3[tid];
    for (int k = 0; k < 256; ++k) c += y2[k] * f_w3[k * 2 + tid];
    sc[tid] = c;
  }
  __syncthreads();
  if (tid == 0) {
    const float s0 = sc[0], s1 = sc[1];
    const float mx = fmaxf(s0, s1);
    const float lse = mx + logf(expf(s0 - mx) + expf(s1 - mx));
    out[n * 2 + 0] = s0 - lse;
    out[n * 2 + 1] = s1 - lse;
  }
}

// ---------------------------------------------------------------------------
extern "C" void kernel_launch(void* const* d_in, const int* in_sizes, int n_in,
                              void* d_out, int out_size, void* d_ws, size_t ws_size,
                              hipStream_t stream) {
  const float* img  = (const float*)d_in[0];
  const float* ques = (const float*)d_in[1];
  const float* g_w1 = (const float*)d_in[2];
  const float* g_b1 = (const float*)d_in[3];
  const float* g_w2 = (const float*)d_in[4];
  const float* g_b2 = (const float*)d_in[5];
  const float* g_w3 = (const float*)d_in[6];
  const float* g_b3 = (const float*)d_in[7];
  const float* g_w4 = (const float*)d_in[8];
  const float* g_b4 = (const float*)d_in[9];
  const float* f_w1 = (const float*)d_in[10];
  const float* f_b1 = (const float*)d_in[11];
  const float* f_w2 = (const float*)d_in[12];
  const float* f_b2 = (const float*)d_in[13];
  const float* f_w3 = (const float*)d_in[14];
  const float* f_b3 = (const float*)d_in[15];
  float* out = (float*)d_out;

  char* ws = (char*)d_ws;
  float*  U    = (float*)(ws);                                 // 4 MB
  float*  V    = (float*)(ws + (size_t)4  * 1048576);          // 4 MB
  float*  part = (float*)(ws + (size_t)8  * 1048576);          // 4 MB
  float*  Qb   = (float*)(ws + (size_t)12 * 1048576);          // 64 KB
  __bf16* W2t  = (__bf16*)(ws + (size_t)12 * 1048576 + 65536); // 128 KB each
  __bf16* W3t  = W2t + 65536;
  __bf16* W4t  = W3t + 65536;

  prep_kernel<<<1136, 256, 0, stream>>>(img, ques, g_w1, g_b1, g_w2, g_w3, g_w4,
                                        U, V, Qb, W2t, W3t, W4t);
  rn_main<<<2048, 512, 0, stream>>>(U, V, Qb, W2t, W3t, W4t, g_b2, g_b3, g_b4, part);
  rn_final<<<64, 1024, 0, stream>>>(part, f_w1, f_b1, f_w2, f_b2, f_w3, f_b3, out);
}